// Round 4
// baseline (93.980 us; speedup 1.0000x reference)
//
#include <hip/hip_runtime.h>

// ---------------------------------------------------------------------------
// MalConvLowMem as GEMM: M=15748 windows (4096 contiguous floats), N=256
// (w1|w2), K=4096; epilogue g=(c1+b1)*sigmoid(c2+b2), max over positions.
// R4: counted-vmcnt pipeline (T3/T4). BM=32,BN=256,BK=64, 512thr/8 waves,
// 2 raw s_barriers per K-step, s_waitcnt vmcnt(5) instead of full drain.
// A staged via global_load_lds as fp32 (1x16B/thread), B via global_load_lds
// bf16 (4x16B/thread); both with pre-inverse-swizzled sources, XOR ^((r&7)<<4).
// LDS 80KB -> 2 blocks/CU.
// ---------------------------------------------------------------------------

#define T_LEN 2000000
#define P_CNT 3937
#define M_TOT 15748
#define KD    4096

typedef __attribute__((ext_vector_type(8))) short short8;
typedef __attribute__((ext_vector_type(4))) float f32x4;

static __device__ __forceinline__ unsigned short f2bf(float f) {
    unsigned u = __builtin_bit_cast(unsigned, f);
    unsigned r = (u + 0x7FFFu + ((u >> 16) & 1u)) >> 16;   // RNE
    return (unsigned short)r;
}

static __device__ __forceinline__ unsigned ordenc(float f) {
    unsigned u = __builtin_bit_cast(unsigned, f);
    return (u & 0x80000000u) ? ~u : (u | 0x80000000u);
}

// row m (clamped) -> flat float offset of window start in x
static __device__ __forceinline__ size_t row_base(int m) {
    if (m > M_TOT - 1) m = M_TOT - 1;
    int bb = m / P_CNT;
    int p  = m - bb * P_CNT;
    int j, kp;
    if (p < 3875) { j = p / 125; kp = p - j * 125; }
    else          { j = 31;      kp = p - 3875; }
    long pos = (long)j * 63489 + (long)kp * 512;
    return ((size_t)bb * T_LEN + (size_t)pos) * 8u;
}

#define GLD_LDS16(gp, lp)                                                      \
    __builtin_amdgcn_global_load_lds(                                          \
        (const __attribute__((address_space(1))) void*)(gp),                   \
        (__attribute__((address_space(3))) void*)(lp), 16, 0, 0)

#define FENCE()   asm volatile("" ::: "memory")
#define WAITVM5() asm volatile("s_waitcnt vmcnt(5)" ::: "memory")
#define WAITVM0() asm volatile("s_waitcnt vmcnt(0)" ::: "memory")
#define WAITLGKM0() asm volatile("s_waitcnt lgkmcnt(0)" ::: "memory")
#define BARRIER() do { FENCE(); __builtin_amdgcn_s_barrier(); FENCE(); } while (0)

// ---------------------------------------------------------------------------
// Kernel 1: repack weights to Bp[n][k] bf16 (n<128: w1, else w2; k=t*8+e),
// init 512 output slots to order-encoded -inf.
// ---------------------------------------------------------------------------
__global__ __launch_bounds__(256) void pack_w(const float* __restrict__ w1,
                                              const float* __restrict__ w2,
                                              unsigned short* __restrict__ Bp,
                                              unsigned* __restrict__ outu) {
    int idx = blockIdx.x * 256 + threadIdx.x;
    if (idx < 512) outu[idx] = 0u;
    if (idx >= 256 * KD) return;
    int n = idx >> 12;
    int k = idx & 4095;
    int e = k & 7;
    int t = k >> 3;
    const float* src = (n < 128) ? w1 : w2;
    Bp[idx] = f2bf(src[(n & 127) * 4096 + e * 512 + t]);
}

// ---------------------------------------------------------------------------
// Kernel 2: fused GEMM + gate + max.
// LDS map: As[2] fp32 32x64 @0,8192 (8KB each); Bs[2] bf16 256x64 @16384,49152
// (32KB each). Total 81920 B. Epilogue reuses [0,32KB) as gt[32][256] f32.
// Per step/thread: 4 gl_lds B + 1 gl_lds A = 5 vmem -> vmcnt(5) retires all
// of the PREVIOUS step's staging regardless of intra-step issue order.
// ---------------------------------------------------------------------------
__global__ __launch_bounds__(512, 4) void gemm_max(const float* __restrict__ x,
                                                   const unsigned short* __restrict__ Bp,
                                                   const float* __restrict__ b1,
                                                   const float* __restrict__ b2,
                                                   unsigned* __restrict__ outu) {
    __shared__ __align__(16) char smem[81920];

    const int t  = threadIdx.x;
    const int m0 = blockIdx.x * 32;

    const int w    = t >> 6;      // wave 0..7
    const int lane = t & 63;
    const int wm   = w >> 2;      // 0..1 (16 rows)
    const int wn   = w & 3;       // 0..3 (64 cols)

    // ---- A staging: thread t writes As linear bytes [16t,16t+16).
    // Pre-inverse-swizzled source: row=t>>4, c' = (t&15) ^ ((t>>4)&7) ----
    const int    rowA  = t >> 4;                       // 0..31
    const size_t asrc0 = row_base(m0 + rowA) + (size_t)((((t & 15) ^ (rowA & 7)) * 4));
    const int    adst  = w * 1024;                     // wave-uniform (+lane*16 by HW)

    // ---- B staging: 4 gl_lds/thread over 32KB; linear dest d ->
    // n=d>>7, kc=((d>>4)&7)^(n&7) (pre-inverse swizzle) ----
    const unsigned short* bsrc[4];
    int bdst[4];
#pragma unroll
    for (int i = 0; i < 4; ++i) {
        int d  = i * 8192 + w * 1024 + lane * 16;
        int n  = d >> 7;
        int kc = ((d >> 4) & 7) ^ (n & 7);
        bsrc[i] = Bp + n * KD + kc * 8;
        bdst[i] = i * 8192 + w * 1024;
    }

    f32x4 acc[4];
#pragma unroll
    for (int nf = 0; nf < 4; ++nf) acc[nf] = (f32x4){0.f, 0.f, 0.f, 0.f};

    // ---- fragment read addresses (step-invariant) ----
    const int rA    = wm * 16 + (lane & 15);
    const int qA    = lane >> 4;
    int aro[2];                                        // per-kq A read offsets
#pragma unroll
    for (int kq = 0; kq < 2; ++kq)
        aro[kq] = (rA * 256 + kq * 128 + qA * 32) ^ ((rA & 7) << 4);
    int bro[2][4];
#pragma unroll
    for (int kq = 0; kq < 2; ++kq)
#pragma unroll
        for (int nf = 0; nf < 4; ++nf) {
            int n = wn * 64 + nf * 16 + (lane & 15);
            bro[kq][nf] = (n * 128 + kq * 64 + (lane >> 4) * 16) ^ ((n & 7) << 4);
        }

    // ---- prologue: stage tile 0 into buf 0 (5 vmem, matching steady state) ----
#pragma unroll
    for (int i = 0; i < 4; ++i) GLD_LDS16(bsrc[i], smem + 16384 + bdst[i]);
    GLD_LDS16(x + asrc0, smem + adst);
    FENCE();

    for (int ks = 0; ks < 64; ++ks) {
        const int cur = ks & 1;
        const int As  = cur * 8192;
        const int Bs  = 16384 + cur * 32768;
        if (ks < 63) {
            // issue next tile into buf cur^1 (safe: barrier2 of ks-1 passed)
            const int kk  = (ks + 1) * 64;
            const int Asn = (cur ^ 1) * 8192;
            const int Bsn = 16384 + (cur ^ 1) * 32768;
#pragma unroll
            for (int i = 0; i < 4; ++i) GLD_LDS16(bsrc[i] + kk, smem + Bsn + bdst[i]);
            GLD_LDS16(x + asrc0 + kk, smem + Asn + adst);
            FENCE();
            WAITVM5();          // retire THIS step's staging; 5 newest stay in flight
        } else {
            WAITVM0();
        }
        BARRIER();              // buf[cur] ready for all waves

        // ---- compute from buf[cur] ----
#pragma unroll
        for (int kq = 0; kq < 2; ++kq) {
            float4 f0 = *(const float4*)(smem + As + aro[kq]);
            float4 f1 = *(const float4*)(smem + As + (aro[kq] ^ 16));
            short8 af;
            af[0] = (short)f2bf(f0.x); af[1] = (short)f2bf(f0.y);
            af[2] = (short)f2bf(f0.z); af[3] = (short)f2bf(f0.w);
            af[4] = (short)f2bf(f1.x); af[5] = (short)f2bf(f1.y);
            af[6] = (short)f2bf(f1.z); af[7] = (short)f2bf(f1.w);
            short8 bfr[4];
#pragma unroll
            for (int nf = 0; nf < 4; ++nf)
                bfr[nf] = *(const short8*)(smem + Bs + bro[kq][nf]);
#pragma unroll
            for (int nf = 0; nf < 4; ++nf)
                acc[nf] = __builtin_amdgcn_mfma_f32_16x16x32_bf16(
                    af, bfr[nf], acc[nf], 0, 0, 0);
        }
        WAITLGKM0();            // LDS reads drained before buf[cur] is rewritten
        BARRIER();              // readers done -> next step may overwrite cur
    }

    __syncthreads();            // full drain before LDS reuse

    // ---- epilogue: spill acc to gt[32][256] f32 ----
    float* gt = (float*)smem;
#pragma unroll
    for (int nf = 0; nf < 4; ++nf) {
        int col = wn * 64 + nf * 16 + (lane & 15);
#pragma unroll
        for (int q = 0; q < 4; ++q) {
            int row = wm * 16 + (lane >> 4) * 4 + q;
            gt[row * 256 + col] = acc[nf][q];
        }
    }
    __syncthreads();

    // ---- gate + per-(b,c) running max + atomicMax ----
    if (t < 128) {
        const int   c   = t;
        const float bb1 = b1[c];
        const float bb2 = b2[c];
        int   bprev = (m0 < M_TOT ? m0 : M_TOT - 1) / P_CNT;
        float best  = -3.4e38f;
        for (int r = 0; r < 32; ++r) {
            int m = m0 + r;
            if (m > M_TOT - 1) m = M_TOT - 1;
            int bb = m / P_CNT;
            float c1 = gt[r * 256 + c] + bb1;
            float c2 = gt[r * 256 + 128 + c] + bb2;
            float g  = c1 / (1.f + __expf(-c2));
            if (bb != bprev) {
                atomicMax(&outu[bprev * 128 + c], ordenc(best));
                bprev = bb;
                best  = -3.4e38f;
            }
            best = fmaxf(best, g);
        }
        atomicMax(&outu[bprev * 128 + c], ordenc(best));
    }
}

// ---------------------------------------------------------------------------
// Kernel 3: decode order-encoded uints to floats in place.
// ---------------------------------------------------------------------------
__global__ __launch_bounds__(256) void unmap_out(unsigned* __restrict__ outu) {
    int i = blockIdx.x * 256 + threadIdx.x;
    if (i < 512) {
        unsigned u = outu[i];
        outu[i] = (u & 0x80000000u) ? (u ^ 0x80000000u) : ~u;
    }
}

extern "C" void kernel_launch(void* const* d_in, const int* in_sizes, int n_in,
                              void* d_out, int out_size, void* d_ws, size_t ws_size,
                              hipStream_t stream) {
    const float* x  = (const float*)d_in[0];
    const float* w1 = (const float*)d_in[1];
    const float* b1 = (const float*)d_in[2];
    const float* w2 = (const float*)d_in[3];
    const float* b2 = (const float*)d_in[4];

    unsigned short* Bp   = (unsigned short*)d_ws;   // 2 MB packed bf16 weights
    unsigned*       outu = (unsigned*)d_out;

    pack_w<<<dim3((256 * KD) / 256), dim3(256), 0, stream>>>(w1, w2, Bp, outu);

    const int nblk = (M_TOT + 31) / 32;             // 493
    gemm_max<<<dim3(nblk), dim3(512), 0, stream>>>(x, Bp, b1, b2, outu);

    unmap_out<<<dim3(2), dim3(256), 0, stream>>>(outu);
}

// Round 5
// 85.573 us; speedup vs baseline: 1.0982x; 1.0982x over previous
//
#include <hip/hip_runtime.h>

// ---------------------------------------------------------------------------
// MalConvLowMem as GEMM: M=15748 windows (4096 contiguous floats), N=256
// (w1|w2), K=4096; epilogue g=(c1+b1)*sigmoid(c2+b2), max over positions.
// R5 = R3 data paths + counted-vmcnt pipeline:
//   per iter: [4x B gl_lds (tile ks+1)] [A global->reg (tile ks+2)]
//             [compute tile ks] [cvt+ds_write A(ks+1)] [vmcnt(1)] [lgkm(0)]
//             [s_barrier]
// vmcnt(1) retires the 4 B loads (issued first = oldest) and leaves the A
// prefetch in flight across the barrier -> 2-body (~1200cy) cover for HBM.
// LDS 72KB (As[2] 4KB @0/4096, Bs[2] 32KB @8192/40960) -> 2 blocks/CU.
// ---------------------------------------------------------------------------

#define T_LEN 2000000
#define P_CNT 3937
#define M_TOT 15748
#define KD    4096

typedef __attribute__((ext_vector_type(8))) short short8;
typedef __attribute__((ext_vector_type(4))) float f32x4;

static __device__ __forceinline__ unsigned short f2bf(float f) {
    unsigned u = __builtin_bit_cast(unsigned, f);
    unsigned r = (u + 0x7FFFu + ((u >> 16) & 1u)) >> 16;   // RNE
    return (unsigned short)r;
}

static __device__ __forceinline__ unsigned ordenc(float f) {
    unsigned u = __builtin_bit_cast(unsigned, f);
    return (u & 0x80000000u) ? ~u : (u | 0x80000000u);
}

// row m (clamped) -> flat float offset of window start in x
static __device__ __forceinline__ size_t row_base(int m) {
    if (m > M_TOT - 1) m = M_TOT - 1;
    int bb = m / P_CNT;
    int p  = m - bb * P_CNT;
    int j, kp;
    if (p < 3875) { j = p / 125; kp = p - j * 125; }
    else          { j = 31;      kp = p - 3875; }
    long pos = (long)j * 63489 + (long)kp * 512;
    return ((size_t)bb * T_LEN + (size_t)pos) * 8u;
}

#define GLD_LDS16(gp, lp)                                                      \
    __builtin_amdgcn_global_load_lds(                                          \
        (const __attribute__((address_space(1))) void*)(gp),                   \
        (__attribute__((address_space(3))) void*)(lp), 16, 0, 0)

#define FENCE()     asm volatile("" ::: "memory")
#define WAITVM1()   asm volatile("s_waitcnt vmcnt(1)" ::: "memory")
#define WAITVM0()   asm volatile("s_waitcnt vmcnt(0)" ::: "memory")
#define WAITLGKM0() asm volatile("s_waitcnt lgkmcnt(0)" ::: "memory")

// ---------------------------------------------------------------------------
// Kernel 1: repack weights to Bp[n][k] bf16 (n<128: w1, else w2; k=t*8+e),
// init 512 output slots to order-encoded -inf.
// ---------------------------------------------------------------------------
__global__ __launch_bounds__(256) void pack_w(const float* __restrict__ w1,
                                              const float* __restrict__ w2,
                                              unsigned short* __restrict__ Bp,
                                              unsigned* __restrict__ outu) {
    int idx = blockIdx.x * 256 + threadIdx.x;
    if (idx < 512) outu[idx] = 0u;
    if (idx >= 256 * KD) return;
    int n = idx >> 12;
    int k = idx & 4095;
    int e = k & 7;
    int t = k >> 3;
    const float* src = (n < 128) ? w1 : w2;
    Bp[idx] = f2bf(src[(n & 127) * 4096 + e * 512 + t]);
}

// ---------------------------------------------------------------------------
// Kernel 2: fused GEMM + gate + max. BM=32 x BN=256, BK=64, 512 thr (8 waves:
// 2M x 4N, each wave 16x64). XOR swizzle ^((row&7)<<4) on As and Bs.
// Epilogue reuses [0,32KB) as gt[32][256] f32.
// ---------------------------------------------------------------------------
__global__ __launch_bounds__(512, 4) void gemm_max(const float* __restrict__ x,
                                                   const unsigned short* __restrict__ Bp,
                                                   const float* __restrict__ b1,
                                                   const float* __restrict__ b2,
                                                   unsigned* __restrict__ outu) {
    __shared__ __align__(16) char smem[73728];

    const int t  = threadIdx.x;
    const int m0 = blockIdx.x * 32;

    const int w    = t >> 6;      // wave 0..7
    const int lane = t & 63;
    const int wm   = w >> 2;      // 0..1 (16 rows)
    const int wn   = w & 3;       // 0..3 (64 cols)

    // ---- A staging: 1 float4/thread: r=t>>4 (0..31), kc=t&15 ----
    const int rAs = t >> 4;
    const int kcA = t & 15;
    const size_t aoff  = row_base(m0 + rAs) + (size_t)(kcA * 4);
    const int    awoff = (rAs * 128 + kcA * 8) ^ ((rAs & 7) << 4);

    // ---- B staging (global_load_lds, 4/thread), pre-inverse-swizzled src:
    // linear dest d -> n=d>>7, kc=((d>>4)&7)^(n&7) ----
    const unsigned short* bsrc[4];
    int bdst[4];
#pragma unroll
    for (int i = 0; i < 4; ++i) {
        int d  = i * 8192 + w * 1024 + lane * 16;
        int n  = d >> 7;
        int kc = ((d >> 4) & 7) ^ (n & 7);
        bsrc[i] = Bp + n * KD + kc * 8;
        bdst[i] = i * 8192 + w * 1024;              // + lane*16 by HW
    }

    f32x4 acc[4];
#pragma unroll
    for (int nf = 0; nf < 4; ++nf) acc[nf] = (f32x4){0.f, 0.f, 0.f, 0.f};

    // ---- fragment read offsets (step-invariant) ----
    const int rA = wm * 16 + (lane & 15);
    int aro[2];
#pragma unroll
    for (int kq = 0; kq < 2; ++kq)
        aro[kq] = (rA * 128 + kq * 64 + (lane >> 4) * 16) ^ ((rA & 7) << 4);
    int bro[2][4];
#pragma unroll
    for (int kq = 0; kq < 2; ++kq)
#pragma unroll
        for (int nf = 0; nf < 4; ++nf) {
            int n = wn * 64 + nf * 16 + (lane & 15);
            bro[kq][nf] = (n * 128 + kq * 64 + (lane >> 4) * 16) ^ ((n & 7) << 4);
        }

    // ---- prologue: B(0) -> Bs[0]; A(0) cvt -> As[0]; A(1) -> regs ----
#pragma unroll
    for (int i = 0; i < 4; ++i) GLD_LDS16(bsrc[i], smem + 8192 + bdst[i]);
    FENCE();
    float4 a0 = *(const float4*)(x + aoff);
    FENCE();
    float4 anext = *(const float4*)(x + aoff + 64);
    FENCE();
    {
        ushort4 h;
        h.x = f2bf(a0.x); h.y = f2bf(a0.y); h.z = f2bf(a0.z); h.w = f2bf(a0.w);
        *(ushort4*)(smem + awoff) = h;              // compiler waits a0 (drains B too; one-time)
    }
    WAITLGKM0();
    FENCE();
    __builtin_amdgcn_s_barrier();
    FENCE();

    for (int ks = 0; ks < 64; ++ks) {
        const int cur = ks & 1;
        const int As  = cur * 4096;
        const int Bs  = 8192 + cur * 32768;
        const int Asn = (cur ^ 1) * 4096;
        const int Bsn = 8192 + (cur ^ 1) * 32768;

        // 1. issue B for tile ks+1 (oldest in queue this iter)
        if (ks < 63) {
            const int kk = (ks + 1) * 64;
#pragma unroll
            for (int i = 0; i < 4; ++i) GLD_LDS16(bsrc[i] + kk, smem + Bsn + bdst[i]);
        }
        FENCE();
        // 2. issue A for tile ks+2 (newest; survives vmcnt(1))
        float4 anext2 = anext;
        if (ks < 62) anext2 = *(const float4*)(x + aoff + (size_t)(ks + 2) * 64);
        FENCE();

        // 3. compute tile ks
#pragma unroll
        for (int kq = 0; kq < 2; ++kq) {
            short8 af = *(const short8*)(smem + As + aro[kq]);
            short8 bfr[4];
#pragma unroll
            for (int nf = 0; nf < 4; ++nf)
                bfr[nf] = *(const short8*)(smem + Bs + bro[kq][nf]);
#pragma unroll
            for (int nf = 0; nf < 4; ++nf)
                acc[nf] = __builtin_amdgcn_mfma_f32_16x16x32_bf16(
                    af, bfr[nf], acc[nf], 0, 0, 0);
        }

        // 4. cvt + write A(ks+1) into As^1 (anext loaded a full iter ago)
        if (ks < 63) {
            ushort4 h;
            h.x = f2bf(anext.x); h.y = f2bf(anext.y);
            h.z = f2bf(anext.z); h.w = f2bf(anext.w);
            *(ushort4*)(smem + Asn + awoff) = h;
        }
        anext = anext2;

        // 5. publish: retire this iter's B (keep A(ks+2) in flight)
        if (ks < 62) { WAITVM1(); } else { WAITVM0(); }
        WAITLGKM0();
        FENCE();
        __builtin_amdgcn_s_barrier();
        FENCE();
    }

    // ---- epilogue: spill acc to gt[32][256] f32 (all reads drained above) ----
    float* gt = (float*)smem;
#pragma unroll
    for (int nf = 0; nf < 4; ++nf) {
        int col = wn * 64 + nf * 16 + (lane & 15);
#pragma unroll
        for (int q = 0; q < 4; ++q) {
            int row = wm * 16 + (lane >> 4) * 4 + q;
            gt[row * 256 + col] = acc[nf][q];
        }
    }
    __syncthreads();

    // ---- gate + per-(b,c) running max + atomicMax ----
    if (t < 128) {
        const int   c   = t;
        const float bb1 = b1[c];
        const float bb2 = b2[c];
        int   bprev = (m0 < M_TOT ? m0 : M_TOT - 1) / P_CNT;
        float best  = -3.4e38f;
        for (int r = 0; r < 32; ++r) {
            int m = m0 + r;
            if (m > M_TOT - 1) m = M_TOT - 1;
            int bb = m / P_CNT;
            float c1 = gt[r * 256 + c] + bb1;
            float c2 = gt[r * 256 + 128 + c] + bb2;
            float g  = c1 / (1.f + __expf(-c2));
            if (bb != bprev) {
                atomicMax(&outu[bprev * 128 + c], ordenc(best));
                bprev = bb;
                best  = -3.4e38f;
            }
            best = fmaxf(best, g);
        }
        atomicMax(&outu[bprev * 128 + c], ordenc(best));
    }
}

// ---------------------------------------------------------------------------
// Kernel 3: decode order-encoded uints to floats in place.
// ---------------------------------------------------------------------------
__global__ __launch_bounds__(256) void unmap_out(unsigned* __restrict__ outu) {
    int i = blockIdx.x * 256 + threadIdx.x;
    if (i < 512) {
        unsigned u = outu[i];
        outu[i] = (u & 0x80000000u) ? (u ^ 0x80000000u) : ~u;
    }
}

extern "C" void kernel_launch(void* const* d_in, const int* in_sizes, int n_in,
                              void* d_out, int out_size, void* d_ws, size_t ws_size,
                              hipStream_t stream) {
    const float* x  = (const float*)d_in[0];
    const float* w1 = (const float*)d_in[1];
    const float* b1 = (const float*)d_in[2];
    const float* w2 = (const float*)d_in[3];
    const float* b2 = (const float*)d_in[4];

    unsigned short* Bp   = (unsigned short*)d_ws;   // 2 MB packed bf16 weights
    unsigned*       outu = (unsigned*)d_out;

    pack_w<<<dim3((256 * KD) / 256), dim3(256), 0, stream>>>(w1, w2, Bp, outu);

    const int nblk = (M_TOT + 31) / 32;             // 493
    gemm_max<<<dim3(nblk), dim3(512), 0, stream>>>(x, Bp, b1, b2, outu);

    unmap_out<<<dim3(2), dim3(256), 0, stream>>>(outu);
}